// Round 1
// 1804.802 us; speedup vs baseline: 1.5050x; 1.5050x over previous
//
#include <hip/hip_runtime.h>
#include <hip/hip_bf16.h>
#include <cstdint>
#include <cstddef>

typedef unsigned short u16;
typedef u16 u16x4 __attribute__((ext_vector_type(4)));
typedef u16 u16x8 __attribute__((ext_vector_type(8)));
typedef __bf16 bf16x8 __attribute__((ext_vector_type(8)));
typedef float f32x4 __attribute__((ext_vector_type(4)));

__device__ __forceinline__ float bf2f(u16 v) {
    union { unsigned u; float f; } x; x.u = ((unsigned)v) << 16; return x.f;
}
__device__ __forceinline__ u16 f2bf(float f) {
    union { float f; unsigned u; } x; x.f = f;
    unsigned u = x.u;
    u += 0x7fffu + ((u >> 16) & 1u);   // round-to-nearest-even
    return (u16)(u >> 16);
}

// async global->LDS, 16B per lane (dest = wave-uniform base + lane*16)
__device__ __forceinline__ void gload_lds16(const void* g, void* l) {
    __builtin_amdgcn_global_load_lds(
        (const __attribute__((address_space(1))) void*)g,
        (__attribute__((address_space(3))) void*)l, 16, 0, 0);
}

// ---------------------------------------------------------------------------
// Small per-launch state in module device memory (frees d_out for W1^T).
// Rewritten deterministically every launch -> graph-replay safe.
// ---------------------------------------------------------------------------
__device__ float          g_gate[4096 * 8];
__device__ int            g_cnt[4096];
__device__ unsigned char  g_bm[4 * 2048];

// bitmap of unmasked positions: g_bm[b*S+p] = 1 iff p unmasked
__global__ void build_bitmap(const int* __restrict__ unm) {
    int tid = threadIdx.x;
    for (int i = tid; i < 4 * 2048; i += 256) g_bm[i] = 0;
    __syncthreads();
    for (int i = tid; i < 4 * 1024; i += 256) {
        int b = i >> 10;
        g_bm[b * 2048 + unm[i]] = 1;
    }
}

// ---------------------------------------------------------------------------
// transpose f32 -> bf16: out[c][r] = bf16(in[r][c]); grid (C/64, R/64, Z)
// ---------------------------------------------------------------------------
__global__ __launch_bounds__(256)
void transpose_g(const float* __restrict__ in, u16* __restrict__ out,
                 int ldi, int ldo, long long zi, long long zo) {
    in  += (size_t)blockIdx.z * zi;
    out += (size_t)blockIdx.z * zo;
    __shared__ u16 s[64][72];
    int tx = threadIdx.x & 15, ty = threadIdx.x >> 4;
    int c0 = blockIdx.x * 64, r0 = blockIdx.y * 64;
#pragma unroll
    for (int i = 0; i < 4; i++) {
        int row = ty + i * 16;
        f32x4 v = *(const f32x4*)(in + (size_t)(r0 + row) * ldi + c0 + tx * 4);
        u16x4 h;
#pragma unroll
        for (int j = 0; j < 4; j++) h[j] = f2bf(v[j]);
        *(u16x4*)&s[row][tx * 4] = h;
    }
    __syncthreads();
#pragma unroll
    for (int i = 0; i < 4; i++) {
        int cc = ty + i * 16;
        u16x4 v;
#pragma unroll
        for (int j = 0; j < 4; j++) v[j] = s[tx * 4 + j][cc];
        *(u16x4*)(out + (size_t)(c0 + cc) * ldo + r0 + tx * 4) = v;
    }
}

// ---------------------------------------------------------------------------
// gather neighbors + routing softmax.  One block per token (B*M = 4096).
// writes X (bf16): [t][0:4096]=h_avg, [t][4096:8192]=h_mask; g_gate, g_cnt.
// ---------------------------------------------------------------------------
__global__ __launch_bounds__(256)
void gather_route(const float* __restrict__ hL, const float* __restrict__ Wr,
                  const float* __restrict__ br, const int* __restrict__ mask_idx,
                  const int* __restrict__ rptr, u16* __restrict__ X) {
    const int S = 2048, D = 4096;
    int t = blockIdx.x;
    int b = t >> 10;
    int tid = threadIdx.x;
    int a = mask_idx[t];
    int r = rptr[0];

    float avg[16];
#pragma unroll
    for (int i = 0; i < 16; i++) avg[i] = 0.f;
    int c = 0;
    for (int j = 0; j < 2 * r; j++) {
        int off = (j < r) ? (j - r) : (j - r + 1);
        int pos = a + off;
        bool ok = (pos >= 0) && (pos < S) && (g_bm[b * S + pos] != 0);
        if (ok) {
            c++;
            const float* rw = hL + (size_t)(b * S + pos) * D + tid * 16;
#pragma unroll
            for (int q = 0; q < 4; q++) {
                f32x4 v = *(const f32x4*)(rw + q * 4);
#pragma unroll
                for (int jj = 0; jj < 4; jj++) avg[q * 4 + jj] += v[jj];
            }
        }
    }
    float inv = 1.0f / (float)(c > 0 ? c : 1);

    const float* rm = hL + (size_t)(b * S + a) * D + tid * 16;
    float part[8];
#pragma unroll
    for (int k = 0; k < 8; k++) part[k] = 0.f;
#pragma unroll
    for (int q = 0; q < 4; q++) {
        f32x4 hm = *(const f32x4*)(rm + q * 4);
        u16x4 xa, xm;
#pragma unroll
        for (int jj = 0; jj < 4; jj++) {
            int d = tid * 16 + q * 4 + jj;
            float hv = hm[jj];
            f32x4 w0 = *(const f32x4*)(Wr + (size_t)d * 8);
            f32x4 w1 = *(const f32x4*)(Wr + (size_t)d * 8 + 4);
#pragma unroll
            for (int k = 0; k < 4; k++) { part[k] += hv * w0[k]; part[k + 4] += hv * w1[k]; }
            xa[jj] = f2bf(avg[q * 4 + jj] * inv);
            xm[jj] = f2bf(hv);
        }
        *(u16x4*)(X + (size_t)t * 8192 + tid * 16 + q * 4) = xa;
        *(u16x4*)(X + (size_t)t * 8192 + 4096 + tid * 16 + q * 4) = xm;
    }

    __shared__ float red[256][8];
#pragma unroll
    for (int k = 0; k < 8; k++) red[tid][k] = part[k];
    __syncthreads();
    for (int s = 128; s > 0; s >>= 1) {
        if (tid < s) {
#pragma unroll
            for (int k = 0; k < 8; k++) red[tid][k] += red[tid + s][k];
        }
        __syncthreads();
    }
    if (tid == 0) {
        float lg[8], mx = -1e30f;
#pragma unroll
        for (int k = 0; k < 8; k++) { lg[k] = red[0][k] + br[k]; mx = fmaxf(mx, lg[k]); }
        float sm = 0.f;
#pragma unroll
        for (int k = 0; k < 8; k++) { lg[k] = expf(lg[k] - mx); sm += lg[k]; }
        float is = 1.0f / sm;
#pragma unroll
        for (int k = 0; k < 8; k++) g_gate[t * 8 + k] = lg[k] * is;
        g_cnt[t] = c;
    }
}

// ---------------------------------------------------------------------------
// GEMM: C[m][n] = sum_k A[m][k]*Bt[n][k].  128x128 tile, BK=64, 256 thr.
// m97 structure: global_load_lds(16B) -> linear LDS [128][64] u16, with the
// XOR chunk-swizzle applied on the GLOBAL source address (rule 21) so that
// ds_read_b128 fragment reads are spread uniformly across all 32 banks.
// MODE 1: out(bf16) = g_gate[row][n>>10] * gelu(acc + bias[col])
// MODE 2: out(f32)  = acc
// ---------------------------------------------------------------------------
template <int MODE>
__global__ __launch_bounds__(256)
void gemm_bt(const u16* __restrict__ A, const u16* __restrict__ Bt,
             void* __restrict__ out, const float* __restrict__ bias,
             int K, int lda, int ldb, int ldc) {
    __shared__ __align__(16) u16 sA[128 * 64];
    __shared__ __align__(16) u16 sB[128 * 64];
    const int tid = threadIdx.x;
    const int w = tid >> 6, lane = tid & 63;
    const int wm = w >> 1, wn = w & 1;
    const int m0 = blockIdx.y * 128, n0 = blockIdx.x * 128;

    f32x4 acc[4][4];
#pragma unroll
    for (int i = 0; i < 4; i++)
#pragma unroll
        for (int j = 0; j < 4; j++) acc[i][j] = (f32x4){0.f, 0.f, 0.f, 0.f};

    // staging geometry: each gload_lds call covers 8 rows x 64 k (1 KiB).
    // lane -> row (lane>>3), 16B chunk (lane&7). Source chunk is XOR-swizzled
    // so stored chunk s of row r holds true chunk s^(r&7).
    const int lrow = lane >> 3;             // 0..7
    const int lchk = (lane & 7) ^ lrow;     // swizzled source chunk
    const u16* gA = A  + (size_t)(m0 + lrow) * lda + lchk * 8;
    const u16* gB = Bt + (size_t)(n0 + lrow) * ldb + lchk * 8;

    for (int k0 = 0; k0 < K; k0 += 64) {
#pragma unroll
        for (int i = 0; i < 4; i++) {
            int g = w * 4 + i;              // row-group 0..15 (wave-uniform)
            gload_lds16(gA + (size_t)(g * 8) * lda + k0, &sA[g * 512]);
            gload_lds16(gB + (size_t)(g * 8) * ldb + k0, &sB[g * 512]);
        }
        __syncthreads();                    // compiler drains vmcnt(0) here
#pragma unroll
        for (int ks = 0; ks < 2; ks++) {
            bf16x8 af[4], bfr[4];
            int c8 = ks * 4 + (lane >> 4);
#pragma unroll
            for (int mi2 = 0; mi2 < 4; mi2++) {
                int ra = wm * 64 + mi2 * 16 + (lane & 15);
                af[mi2] = *(const bf16x8*)(sA + ra * 64 + ((c8 ^ (ra & 7)) * 8));
            }
#pragma unroll
            for (int ni = 0; ni < 4; ni++) {
                int rb = wn * 64 + ni * 16 + (lane & 15);
                bfr[ni] = *(const bf16x8*)(sB + rb * 64 + ((c8 ^ (rb & 7)) * 8));
            }
#pragma unroll
            for (int mi2 = 0; mi2 < 4; mi2++)
#pragma unroll
                for (int ni = 0; ni < 4; ni++)
                    acc[mi2][ni] = __builtin_amdgcn_mfma_f32_16x16x32_bf16(
                        af[mi2], bfr[ni], acc[mi2][ni], 0, 0, 0);
        }
        __syncthreads();
    }

    const int colb = n0 + wn * 64 + (lane & 15);
    const int rowb = m0 + wm * 64 + ((lane >> 4) << 2);
    if (MODE == 1) {
        u16* O = (u16*)out;
        const int e = n0 >> 10;             // expert id (uniform per block)
#pragma unroll
        for (int ni = 0; ni < 4; ni++) {
            int col = colb + ni * 16;
            float bv = bias[col];
#pragma unroll
            for (int mi2 = 0; mi2 < 4; mi2++) {
#pragma unroll
                for (int rr2 = 0; rr2 < 4; rr2++) {
                    int row = rowb + mi2 * 16 + rr2;
                    float x = acc[mi2][ni][rr2] + bv;
                    float gel = 0.5f * x * (1.0f + erff(x * 0.70710678118654752f));
                    O[(size_t)row * ldc + col] = f2bf(gel * g_gate[row * 8 + e]);
                }
            }
        }
    } else {
        float* O = (float*)out;
#pragma unroll
        for (int ni = 0; ni < 4; ni++) {
            int col = colb + ni * 16;
#pragma unroll
            for (int mi2 = 0; mi2 < 4; mi2++) {
#pragma unroll
                for (int rr2 = 0; rr2 < 4; rr2++) {
                    int row = rowb + mi2 * 16 + rr2;
                    O[(size_t)row * ldc + col] = acc[mi2][ni][rr2];
                }
            }
        }
    }
}

// ---------------------------------------------------------------------------
// LayerNorm (+ gate-weighted b2 bias) -> writes f32 row straight into d_out
// at position (b, mask_indices[b][m]). cnt==0 rows -> zeros.
// ---------------------------------------------------------------------------
__global__ __launch_bounds__(256)
void ln_kernel(const float* __restrict__ EO, const float* __restrict__ b2,
               const int* __restrict__ mi, float* __restrict__ out) {
    const int D = 4096;
    int t = blockIdx.x, tid = threadIdx.x;
    int p = (t >> 10) * 2048 + mi[t];
    float* orow = out + (size_t)p * D;
    if (g_cnt[t] == 0) {
        f32x4 z = (f32x4){0.f, 0.f, 0.f, 0.f};
#pragma unroll
        for (int i = 0; i < 4; i++) *(f32x4*)(orow + i * 1024 + tid * 4) = z;
        return;
    }
    float g[8];
#pragma unroll
    for (int k = 0; k < 8; k++) g[k] = g_gate[t * 8 + k];

    float vals[16];
    float sum = 0.f, sq = 0.f;
#pragma unroll
    for (int i = 0; i < 4; i++) {
        int d = i * 1024 + tid * 4;
        f32x4 v = *(const f32x4*)(EO + (size_t)t * D + d);
#pragma unroll
        for (int k = 0; k < 8; k++) {
            f32x4 bb = *(const f32x4*)(b2 + (size_t)k * D + d);
            float gk = g[k];
#pragma unroll
            for (int j = 0; j < 4; j++) v[j] += gk * bb[j];
        }
#pragma unroll
        for (int j = 0; j < 4; j++) { vals[i * 4 + j] = v[j]; sum += v[j]; sq += v[j] * v[j]; }
    }
    __shared__ float rs[256], rq[256];
    rs[tid] = sum; rq[tid] = sq;
    __syncthreads();
    for (int s = 128; s > 0; s >>= 1) {
        if (tid < s) { rs[tid] += rs[tid + s]; rq[tid] += rq[tid + s]; }
        __syncthreads();
    }
    float mean = rs[0] * (1.0f / 4096.0f);
    float var = rq[0] * (1.0f / 4096.0f) - mean * mean;
    float rstd = rsqrtf(var + 1e-5f);
#pragma unroll
    for (int i = 0; i < 4; i++) {
        int d = i * 1024 + tid * 4;
        f32x4 o;
#pragma unroll
        for (int j = 0; j < 4; j++) o[j] = (vals[i * 4 + j] - mean) * rstd;
        *(f32x4*)(orow + d) = o;
    }
}

// zero the unmasked rows of d_out (masked/unmasked partition all of S)
__global__ __launch_bounds__(256)
void zero_fill(const int* __restrict__ ui, float* __restrict__ out) {
    int i = blockIdx.x;
    int p = (i >> 10) * 2048 + ui[i];
    float* orow = out + (size_t)p * 4096;
    f32x4 z = (f32x4){0.f, 0.f, 0.f, 0.f};
#pragma unroll
    for (int q = 0; q < 4; q++) *(f32x4*)(orow + q * 1024 + threadIdx.x * 4) = z;
}

// ---------------------------------------------------------------------------
// Memory plan:
//   d_ws (128 MiB):
//     [0,   64Mi)  X (bf16 [4096][8192])  -> reused as EO (f32 [4096][4096])
//     [64Mi,128Mi) HG (bf16 [4096][8192])
//   d_out (128 MiB) as scratch until the LN/zero-fill passes:
//     W1T (bf16 [8192][8192], 128 MiB) during GEMM1,
//     then W2T (bf16 [4096][8192], 64 MiB) during GEMM2.
//   gate/cnt/bitmap live in __device__ globals.
//   ln_kernel + zero_fill together write every d_out element exactly once.
// ---------------------------------------------------------------------------
extern "C" void kernel_launch(void* const* d_in, const int* in_sizes, int n_in,
                              void* d_out, int out_size, void* d_ws, size_t ws_size,
                              hipStream_t stream) {
    const float* hL = (const float*)d_in[0];
    const float* Wr = (const float*)d_in[1];
    const float* br = (const float*)d_in[2];
    const float* W1 = (const float*)d_in[3];
    const float* b1 = (const float*)d_in[4];
    const float* W2 = (const float*)d_in[5];
    const float* b2 = (const float*)d_in[6];
    const int* mi = (const int*)d_in[7];
    const int* ui = (const int*)d_in[8];
    const int* rr = (const int*)d_in[9];

    char* ws = (char*)d_ws;
    u16* X   = (u16*)ws;
    float* EO = (float*)ws;
    u16* HG  = (u16*)(ws + (size_t)64 * 1024 * 1024);
    u16* W1T = (u16*)d_out;
    u16* W2T = (u16*)d_out;

    build_bitmap<<<dim3(1), dim3(256), 0, stream>>>(ui);
    gather_route<<<dim3(4096), dim3(256), 0, stream>>>(hL, Wr, br, mi, rr, X);

    // W1 (8 experts, [8192][1024] each) -> W1T [8192 n][8192 k], one launch
    transpose_g<<<dim3(16, 128, 8), dim3(256), 0, stream>>>(
        W1, W1T, 1024, 8192, 8388608LL, 8388608LL);
    // fused GEMM1 over all experts: HG = gate * gelu(X @ W1 + b1)
    gemm_bt<1><<<dim3(64, 32), dim3(256), 0, stream>>>(
        X, W1T, (void*)HG, b1, 8192, 8192, 8192, 8192);

    // W2 ([8192][4096] flat) -> W2T [4096][8192] (overwrites W1T, stream-ordered)
    transpose_g<<<dim3(64, 128, 1), dim3(256), 0, stream>>>(
        W2, W2T, 4096, 8192, 0, 0);
    // fused GEMM2: EO = HG @ W2flat
    gemm_bt<2><<<dim3(32, 32), dim3(256), 0, stream>>>(
        HG, W2T, (void*)EO, (const float*)nullptr, 8192, 8192, 8192, 4096);

    ln_kernel<<<dim3(4096), dim3(256), 0, stream>>>(EO, b2, mi, (float*)d_out);
    zero_fill<<<dim3(4096), dim3(256), 0, stream>>>(ui, (float*)d_out);
}